// Round 1
// 207.380 us; speedup vs baseline: 2.2520x; 2.2520x over previous
//
#include <hip/hip_runtime.h>
#include <math.h>

// Problem constants (fixed by setup_inputs)
#define BB  16      // batch
#define SS  1024    // spans
#define CC  16      // candidates per span
#define LL  256     // unique links
#define SCW 1041    // 1 + CC + SS  (scores row width)

#define TCH 16              // t-rows per kMVp chunk
#define NCH (SS / TCH)      // 64 chunks -> 64*16 = 1024 blocks

// ---------------------------------------------------------------------------
// block-wide sum reduction (blockDim multiple of 64, <=1024), lds >= 16 floats
__device__ __forceinline__ float blockReduceSum(float v, float* lds) {
#pragma unroll
    for (int o = 32; o > 0; o >>= 1) v += __shfl_down(v, o, 64);
    int lane = threadIdx.x & 63;
    int wid  = threadIdx.x >> 6;
    int nw   = blockDim.x >> 6;
    if (lane == 0) lds[wid] = v;
    __syncthreads();
    v = (threadIdx.x < nw) ? lds[threadIdx.x] : 0.0f;
    if (wid == 0) {
#pragma unroll
        for (int o = 8; o > 0; o >>= 1) v += __shfl_down(v, o, 64);
        if (lane == 0) lds[0] = v;
    }
    __syncthreads();
    v = lds[0];
    __syncthreads();
    return v;
}

// ---------------------------------------------------------------------------
// zero n contiguous floats (xA, xB, tr2 live contiguously in ws)
__global__ void kInit(float* p, int n) {
    int i = blockIdx.x * blockDim.x + threadIdx.x;
    if (i < n) p[i] = 0.0f;
}

// ---------------------------------------------------------------------------
// One workgroup per (b, t) column of W. Computes
//   D_t = exp(root) + sum_l cnt_l*exp(sumscore_l) + sum_{s != t} exp(sc[b,t,17+s])
// writes invD, logD.
__global__ __launch_bounds__(256) void kD(const float* __restrict__ scores,
                                          const int*   __restrict__ cand,
                                          const int*   __restrict__ ul,
                                          float* __restrict__ invD,
                                          float* __restrict__ logD) {
    int bt = blockIdx.x;             // b*SS + t
    int b  = bt >> 10;
    int t  = bt & (SS - 1);
    const float* sc = scores + (size_t)bt * SCW;
    __shared__ int   uls[LL];
    __shared__ int   cands[CC];
    __shared__ float cscs[CC];
    __shared__ float red[16];
    int tid = threadIdx.x;

    uls[tid] = ul[b * LL + tid];                       // blockDim == LL == 256
    if (tid < CC) {
        cands[tid] = cand[(size_t)bt * CC + tid];
        cscs[tid]  = sc[1 + tid];
    }
    __syncthreads();

    float p = 0.0f;
#pragma unroll
    for (int r = 0; r < SS / 256; ++r) {
        int s = tid + r * 256;
        float v = sc[1 + CC + s];
        if (s != t) p += expf(v);
    }
    if (tid == 0) p += expf(sc[0]);                    // root -> span edge

    // link -> span edges: thread tid handles link index tid.
    {
        int lv = uls[tid];
        int   cnt = 0;
        float ssum = 0.0f;
#pragma unroll
        for (int c = 0; c < CC; ++c) {
            bool m = (cands[c] == lv);
            cnt += m ? 1 : 0;
            ssum += m ? cscs[c] : 0.0f;
        }
        if (cnt) p += (float)cnt * expf(ssum);
    }

    float Dv = blockReduceSum(p, red);
    if (tid == 0) {
        invD[bt] = 1.0f / Dv;
        logD[bt] = logf(Dv);
    }
}

// ---------------------------------------------------------------------------
// tr(R^2) = sum_{s != t} exp(sc[b,t,17+s] + sc[b,s,17+t]) * invD_t * invD_s
// 64x64 tiles; the mirrored tile is staged through LDS (transposed store).
__global__ __launch_bounds__(256) void kTr2(const float* __restrict__ scores,
                                            const float* __restrict__ invD,
                                            float* __restrict__ tr2) {
    int si = blockIdx.x, ti = blockIdx.y, b = blockIdx.z;
    int s0 = si * 64, t0 = ti * 64;
    const float* sb = scores + (size_t)b * SS * SCW;
    __shared__ float T2t[64][65];
    __shared__ float red[16];
    int tid  = threadIdx.x;
    int lane = tid & 63;
    int row4 = tid >> 6;

    // load mirrored tile: T2t[i][j] = sc(b, s0+j, 17 + t0 + i)
#pragma unroll
    for (int r = 0; r < 16; ++r) {
        int j = r * 4 + row4;
        T2t[lane][j] = sb[(size_t)(s0 + j) * SCW + 1 + CC + t0 + lane];
    }
    __syncthreads();

    float ivs = invD[b * SS + s0 + lane];
    float acc = 0.0f;
#pragma unroll
    for (int r = 0; r < 16; ++r) {
        int i  = r * 4 + row4;
        int tg = t0 + i;
        float ivt = invD[b * SS + tg];
        float a = sb[(size_t)tg * SCW + 1 + CC + s0 + lane];
        float bt2 = T2t[i][lane];
        if (tg != s0 + lane) acc += expf(a + bt2) * ivt * ivs;
    }
    float tot = blockReduceSum(acc, red);
    if (tid == 0) atomicAdd(&tr2[b], tot);
}

// ---------------------------------------------------------------------------
// Partial matvec: for t in [t0, t0+TCH), accumulate
//   x[b][s] += sum_{t != s} exp(sc[b,t,17+s]) * zin[b][t]
// Grid (NCH, BB), 256 threads; thread owns columns {tid, tid+256, tid+512, tid+768}.
// Coalesced dword reads (wave reads 256B contiguous per row segment), 16-deep
// unroll gives the scheduler 64 outstanding loads per thread.
__global__ __launch_bounds__(256) void kMVp(const float* __restrict__ scores,
                                            const float* __restrict__ zin,
                                            float* __restrict__ xout) {
    int b   = blockIdx.y;
    int t0  = blockIdx.x * TCH;
    int tid = threadIdx.x;
    __shared__ float zl[TCH];
    if (tid < TCH) zl[tid] = zin[b * SS + t0 + tid];
    __syncthreads();

    float acc0 = 0.0f, acc1 = 0.0f, acc2 = 0.0f, acc3 = 0.0f;
    const float* base = scores + (size_t)(b * SS + t0) * SCW + 1 + CC;
#pragma unroll
    for (int r = 0; r < TCH; ++r) {
        const float* rp = base + (size_t)r * SCW;
        float z = zl[r];
        int   t = t0 + r;
        float v0 = rp[tid];
        float v1 = rp[tid + 256];
        float v2 = rp[tid + 512];
        float v3 = rp[tid + 768];
        acc0 += (t != tid)       ? expf(v0) * z : 0.0f;
        acc1 += (t != tid + 256) ? expf(v1) * z : 0.0f;
        acc2 += (t != tid + 512) ? expf(v2) * z : 0.0f;
        acc3 += (t != tid + 768) ? expf(v3) * z : 0.0f;
    }
    float* xo = xout + b * SS;
    atomicAdd(&xo[tid],       acc0);
    atomicAdd(&xo[tid + 256], acc1);
    atomicAdd(&xo[tid + 512], acc2);
    atomicAdd(&xo[tid + 768], acc3);
}

// ---------------------------------------------------------------------------
// z = x * invD elementwise; also re-zero the buffer the NEXT matvec will
// accumulate into (zeroBuf may alias an x no longer needed).
__global__ __launch_bounds__(256) void kZ(const float* __restrict__ x,
                                          const float* __restrict__ invD,
                                          float* __restrict__ z,
                                          float* __restrict__ zeroBuf) {
    int i = blockIdx.x * 256 + threadIdx.x;   // grid = BB*SS/256 blocks
    z[i] = x[i] * invD[i];
    if (zeroBuf) zeroBuf[i] = 0.0f;
}

// ---------------------------------------------------------------------------
// out = mean_b [ sum_t logD + log(1-lam) + lam - 0.5*(tr2 - lam^2) ],
// lam = <x4,x3>/<x3,x3>  (power-iteration Rayleigh ratio)
__global__ __launch_bounds__(1024) void kFin(const float* __restrict__ x3,
                                             const float* __restrict__ x4,
                                             const float* __restrict__ logD,
                                             const float* __restrict__ tr2,
                                             float* __restrict__ out) {
    __shared__ float red[16];
    int tid = threadIdx.x;
    float total = 0.0f;
    for (int b = 0; b < BB; ++b) {
        float a  = x3[b * SS + tid];
        float c  = x4[b * SS + tid];
        float lg = logD[b * SS + tid];
        float d34 = blockReduceSum(a * c, red);
        float d33 = blockReduceSum(a * a, red);
        float slg = blockReduceSum(lg, red);
        if (tid == 0) {
            float lam = d34 / d33;
            total += slg + log1pf(-lam) + lam - 0.5f * (tr2[b] - lam * lam);
        }
    }
    if (tid == 0) out[0] = total / (float)BB;
}

// ---------------------------------------------------------------------------
extern "C" void kernel_launch(void* const* d_in, const int* in_sizes, int n_in,
                              void* d_out, int out_size, void* d_ws, size_t ws_size,
                              hipStream_t stream) {
    const float* scores = (const float*)d_in[0];
    const int*   cand   = (const int*)d_in[1];
    const int*   ul     = (const int*)d_in[2];
    float* out = (float*)d_out;

    float* ws   = (float*)d_ws;
    float* invD = ws;                 // BB*SS
    float* logD = invD + BB * SS;     // BB*SS
    float* xA   = logD + BB * SS;     // BB*SS  (x1, then x3)
    float* xB   = xA   + BB * SS;     // BB*SS  (x2, then x4)
    float* tr2  = xB   + BB * SS;     // BB     (contiguous with xA/xB for kInit)
    float* z    = tr2  + BB;          // BB*SS  (current z vector)

    // zero xA, xB, tr2 in one contiguous sweep
    int nz = 2 * BB * SS + BB;
    kInit<<<dim3((nz + 255) / 256), dim3(256), 0, stream>>>(xA, nz);

    kD<<<dim3(BB * SS), dim3(256), 0, stream>>>(scores, cand, ul, invD, logD);
    kTr2<<<dim3(SS / 64, SS / 64, BB), dim3(256), 0, stream>>>(scores, invD, tr2);

    // power iteration: x0 = ones  =>  z0 = invD
    dim3 mvGrid(NCH, BB);
    kMVp<<<mvGrid, dim3(256), 0, stream>>>(scores, invD, xA);            // x1 -> xA
    kZ<<<dim3(BB * SS / 256), dim3(256), 0, stream>>>(xA, invD, z, (float*)nullptr);
    kMVp<<<mvGrid, dim3(256), 0, stream>>>(scores, z, xB);               // x2 -> xB
    kZ<<<dim3(BB * SS / 256), dim3(256), 0, stream>>>(xB, invD, z, xA);  // zero xA for x3
    kMVp<<<mvGrid, dim3(256), 0, stream>>>(scores, z, xA);               // x3 -> xA
    kZ<<<dim3(BB * SS / 256), dim3(256), 0, stream>>>(xA, invD, z, xB);  // zero xB for x4
    kMVp<<<mvGrid, dim3(256), 0, stream>>>(scores, z, xB);               // x4 -> xB

    kFin<<<dim3(1), dim3(1024), 0, stream>>>(xA, xB, logD, tr2, out);
}

// Round 2
// 171.886 us; speedup vs baseline: 2.7170x; 1.2065x over previous
//
#include <hip/hip_runtime.h>
#include <math.h>

// Problem constants (fixed by setup_inputs)
#define BB  16      // batch
#define SS  1024    // spans
#define CC  16      // candidates per span
#define LL  256     // unique links
#define SCW 1041    // 1 + CC + SS  (scores row width)

#define TCH 16              // t-rows per kMVp chunk
#define NCH (SS / TCH)      // 64 chunks -> 64*16 = 1024 blocks
#define NT  (SS / 64)       // 16 tiles per axis in kTr2

// ---------------------------------------------------------------------------
// block-wide sum reduction (blockDim multiple of 64, <=1024), lds >= 16 floats
__device__ __forceinline__ float blockReduceSum(float v, float* lds) {
#pragma unroll
    for (int o = 32; o > 0; o >>= 1) v += __shfl_down(v, o, 64);
    int lane = threadIdx.x & 63;
    int wid  = threadIdx.x >> 6;
    int nw   = blockDim.x >> 6;
    if (lane == 0) lds[wid] = v;
    __syncthreads();
    v = (threadIdx.x < nw) ? lds[threadIdx.x] : 0.0f;
    if (wid == 0) {
#pragma unroll
        for (int o = 8; o > 0; o >>= 1) v += __shfl_down(v, o, 64);
        if (lane == 0) lds[0] = v;
    }
    __syncthreads();
    v = lds[0];
    __syncthreads();
    return v;
}

// ---------------------------------------------------------------------------
// zero n contiguous floats
__global__ void kInit(float* p, int n) {
    int i = blockIdx.x * blockDim.x + threadIdx.x;
    if (i < n) p[i] = 0.0f;
}

// ---------------------------------------------------------------------------
// One workgroup per (b, t) column of W. Computes
//   D_t = exp(root) + sum_l cnt_l*exp(sumscore_l) + sum_{s != t} exp(sc[b,t,17+s])
// writes invD, logD.
__global__ __launch_bounds__(256) void kD(const float* __restrict__ scores,
                                          const int*   __restrict__ cand,
                                          const int*   __restrict__ ul,
                                          float* __restrict__ invD,
                                          float* __restrict__ logD) {
    int bt = blockIdx.x;             // b*SS + t
    int b  = bt >> 10;
    int t  = bt & (SS - 1);
    const float* sc = scores + (size_t)bt * SCW;
    __shared__ int   uls[LL];
    __shared__ int   cands[CC];
    __shared__ float cscs[CC];
    __shared__ float red[16];
    int tid = threadIdx.x;

    uls[tid] = ul[b * LL + tid];                       // blockDim == LL == 256
    if (tid < CC) {
        cands[tid] = cand[(size_t)bt * CC + tid];
        cscs[tid]  = sc[1 + tid];
    }
    __syncthreads();

    float p = 0.0f;
#pragma unroll
    for (int r = 0; r < SS / 256; ++r) {
        int s = tid + r * 256;
        float v = sc[1 + CC + s];
        if (s != t) p += expf(v);
    }
    if (tid == 0) p += expf(sc[0]);                    // root -> span edge

    // link -> span edges: thread tid handles link index tid.
    {
        int lv = uls[tid];
        int   cnt = 0;
        float ssum = 0.0f;
#pragma unroll
        for (int c = 0; c < CC; ++c) {
            bool m = (cands[c] == lv);
            cnt += m ? 1 : 0;
            ssum += m ? cscs[c] : 0.0f;
        }
        if (cnt) p += (float)cnt * expf(ssum);
    }

    float Dv = blockReduceSum(p, red);
    if (tid == 0) {
        invD[bt] = 1.0f / Dv;
        logD[bt] = logf(Dv);
    }
}

// ---------------------------------------------------------------------------
// tr(R^2) = sum_{s != t} exp(sc[b,t,17+s] + sc[b,s,17+t]) * invD_t * invD_s
// The summand is symmetric in (s,t): only tiles with si <= ti are computed;
// off-diagonal tiles count double. Per-block partial -> part[b][ti][si]
// (NO atomics: 4096 atomicAdds onto one 64B line serialized across XCDs).
__global__ __launch_bounds__(256) void kTr2(const float* __restrict__ scores,
                                            const float* __restrict__ invD,
                                            float* __restrict__ part) {
    int si = blockIdx.x, ti = blockIdx.y, b = blockIdx.z;
    int pidx = (b * NT + ti) * NT + si;
    int tid  = threadIdx.x;
    if (si > ti) {                      // lower triangle: nothing to do
        if (tid == 0) part[pidx] = 0.0f;
        return;
    }
    int s0 = si * 64, t0 = ti * 64;
    const float* sb = scores + (size_t)b * SS * SCW;
    __shared__ float T2t[64][65];
    __shared__ float red[16];
    int lane = tid & 63;
    int row4 = tid >> 6;

    // load mirrored tile: T2t[i][j] = sc(b, s0+j, 17 + t0 + i)
#pragma unroll
    for (int r = 0; r < 16; ++r) {
        int j = r * 4 + row4;
        T2t[lane][j] = sb[(size_t)(s0 + j) * SCW + 1 + CC + t0 + lane];
    }
    __syncthreads();

    float ivs = invD[b * SS + s0 + lane];
    float acc = 0.0f;
#pragma unroll
    for (int r = 0; r < 16; ++r) {
        int i  = r * 4 + row4;
        int tg = t0 + i;
        float ivt = invD[b * SS + tg];
        float a = sb[(size_t)tg * SCW + 1 + CC + s0 + lane];
        float bt2 = T2t[i][lane];
        if (tg != s0 + lane) acc += expf(a + bt2) * ivt * ivs;
    }
    float tot = blockReduceSum(acc, red);
    if (tid == 0) part[pidx] = (si == ti) ? tot : 2.0f * tot;
}

// ---------------------------------------------------------------------------
// Partial matvec: for t in [t0, t0+TCH), accumulate
//   x[b][s] += sum_{t != s} exp(sc[b,t,17+s]) * zin[b][t]
__global__ __launch_bounds__(256) void kMVp(const float* __restrict__ scores,
                                            const float* __restrict__ zin,
                                            float* __restrict__ xout) {
    int b   = blockIdx.y;
    int t0  = blockIdx.x * TCH;
    int tid = threadIdx.x;
    __shared__ float zl[TCH];
    if (tid < TCH) zl[tid] = zin[b * SS + t0 + tid];
    __syncthreads();

    float acc0 = 0.0f, acc1 = 0.0f, acc2 = 0.0f, acc3 = 0.0f;
    const float* base = scores + (size_t)(b * SS + t0) * SCW + 1 + CC;
#pragma unroll
    for (int r = 0; r < TCH; ++r) {
        const float* rp = base + (size_t)r * SCW;
        float z = zl[r];
        int   t = t0 + r;
        float v0 = rp[tid];
        float v1 = rp[tid + 256];
        float v2 = rp[tid + 512];
        float v3 = rp[tid + 768];
        acc0 += (t != tid)       ? expf(v0) * z : 0.0f;
        acc1 += (t != tid + 256) ? expf(v1) * z : 0.0f;
        acc2 += (t != tid + 512) ? expf(v2) * z : 0.0f;
        acc3 += (t != tid + 768) ? expf(v3) * z : 0.0f;
    }
    float* xo = xout + b * SS;
    atomicAdd(&xo[tid],       acc0);
    atomicAdd(&xo[tid + 256], acc1);
    atomicAdd(&xo[tid + 512], acc2);
    atomicAdd(&xo[tid + 768], acc3);
}

// ---------------------------------------------------------------------------
// z = x * invD elementwise; also re-zero the buffer the NEXT matvec will
// accumulate into (zeroBuf may alias an x no longer needed).
__global__ __launch_bounds__(256) void kZ(const float* __restrict__ x,
                                          const float* __restrict__ invD,
                                          float* __restrict__ z,
                                          float* __restrict__ zeroBuf) {
    int i = blockIdx.x * 256 + threadIdx.x;   // grid = BB*SS/256 blocks
    z[i] = x[i] * invD[i];
    if (zeroBuf) zeroBuf[i] = 0.0f;
}

// ---------------------------------------------------------------------------
// out = mean_b [ sum_t logD + log(1-lam) + lam - 0.5*(tr2 - lam^2) ],
// lam = <x4,x3>/<x3,x3>  (power-iteration Rayleigh ratio)
// tr2 is reduced here from the 256 per-tile partials of kTr2.
__global__ __launch_bounds__(1024) void kFin(const float* __restrict__ x3,
                                             const float* __restrict__ x4,
                                             const float* __restrict__ logD,
                                             const float* __restrict__ part,
                                             float* __restrict__ out) {
    __shared__ float red[16];
    int tid = threadIdx.x;
    float total = 0.0f;
    for (int b = 0; b < BB; ++b) {
        float a  = x3[b * SS + tid];
        float c  = x4[b * SS + tid];
        float lg = logD[b * SS + tid];
        float pv = (tid < NT * NT) ? part[b * NT * NT + tid] : 0.0f;
        float d34 = blockReduceSum(a * c, red);
        float d33 = blockReduceSum(a * a, red);
        float slg = blockReduceSum(lg, red);
        float t2  = blockReduceSum(pv, red);
        if (tid == 0) {
            float lam = d34 / d33;
            total += slg + log1pf(-lam) + lam - 0.5f * (t2 - lam * lam);
        }
    }
    if (tid == 0) out[0] = total / (float)BB;
}

// ---------------------------------------------------------------------------
extern "C" void kernel_launch(void* const* d_in, const int* in_sizes, int n_in,
                              void* d_out, int out_size, void* d_ws, size_t ws_size,
                              hipStream_t stream) {
    const float* scores = (const float*)d_in[0];
    const int*   cand   = (const int*)d_in[1];
    const int*   ul     = (const int*)d_in[2];
    float* out = (float*)d_out;

    float* ws   = (float*)d_ws;
    float* invD = ws;                 // BB*SS
    float* logD = invD + BB * SS;     // BB*SS
    float* xA   = logD + BB * SS;     // BB*SS  (x1, then x3)
    float* xB   = xA   + BB * SS;     // BB*SS  (x2, then x4)
    float* z    = xB   + BB * SS;     // BB*SS  (current z vector)
    float* part = z    + BB * SS;     // BB*NT*NT (kTr2 per-tile partials)

    // zero xA, xB in one contiguous sweep (xA,xB adjacent)
    int nz = 2 * BB * SS;
    kInit<<<dim3((nz + 255) / 256), dim3(256), 0, stream>>>(xA, nz);

    kD<<<dim3(BB * SS), dim3(256), 0, stream>>>(scores, cand, ul, invD, logD);
    kTr2<<<dim3(NT, NT, BB), dim3(256), 0, stream>>>(scores, invD, part);

    // power iteration: x0 = ones  =>  z0 = invD
    dim3 mvGrid(NCH, BB);
    kMVp<<<mvGrid, dim3(256), 0, stream>>>(scores, invD, xA);            // x1 -> xA
    kZ<<<dim3(BB * SS / 256), dim3(256), 0, stream>>>(xA, invD, z, (float*)nullptr);
    kMVp<<<mvGrid, dim3(256), 0, stream>>>(scores, z, xB);               // x2 -> xB
    kZ<<<dim3(BB * SS / 256), dim3(256), 0, stream>>>(xB, invD, z, xA);  // zero xA for x3
    kMVp<<<mvGrid, dim3(256), 0, stream>>>(scores, z, xA);               // x3 -> xA
    kZ<<<dim3(BB * SS / 256), dim3(256), 0, stream>>>(xA, invD, z, xB);  // zero xB for x4
    kMVp<<<mvGrid, dim3(256), 0, stream>>>(scores, z, xB);               // x4 -> xB

    kFin<<<dim3(1), dim3(1024), 0, stream>>>(xA, xB, logD, part, out);
}

// Round 3
// 137.958 us; speedup vs baseline: 3.3853x; 1.2459x over previous
//
#include <hip/hip_runtime.h>
#include <math.h>

// Problem constants (fixed by setup_inputs)
#define BB  16      // batch
#define SS  1024    // spans
#define CC  16      // candidates per span
#define LL  256     // unique links
#define SCW 1041    // 1 + CC + SS  (scores row width)
#define NTAB 5000   // candidate/link id space

#define TCH 16              // t-rows per kMVp chunk
#define NCH (SS / TCH)      // 64 chunks -> 64*16 = 1024 blocks
#define NT  (SS / 64)       // 16 tiles per axis in kTr2

// ---------------------------------------------------------------------------
// block-wide sum reduction (blockDim multiple of 64, <=1024), lds >= 16 floats
__device__ __forceinline__ float blockReduceSum(float v, float* lds) {
#pragma unroll
    for (int o = 32; o > 0; o >>= 1) v += __shfl_down(v, o, 64);
    int lane = threadIdx.x & 63;
    int wid  = threadIdx.x >> 6;
    int nw   = blockDim.x >> 6;
    if (lane == 0) lds[wid] = v;
    __syncthreads();
    v = (threadIdx.x < nw) ? lds[threadIdx.x] : 0.0f;
    if (wid == 0) {
#pragma unroll
        for (int o = 8; o > 0; o >>= 1) v += __shfl_down(v, o, 64);
        if (lane == 0) lds[0] = v;
    }
    __syncthreads();
    v = lds[0];
    __syncthreads();
    return v;
}

// ---------------------------------------------------------------------------
// zero n contiguous floats (also used to zero the int count table: 0.0f == 0)
__global__ void kInit(float* p, int n) {
    int i = blockIdx.x * blockDim.x + threadIdx.x;
    if (i < n) p[i] = 0.0f;
}

// ---------------------------------------------------------------------------
// per-batch link-id multiplicity table: cnt[b][id] = #occurrences in unique_links
__global__ __launch_bounds__(256) void kCount(const int* __restrict__ ul,
                                              int* __restrict__ cnt) {
    int b = blockIdx.x;
    int tid = threadIdx.x;                 // blockDim == LL == 256
    atomicAdd(&cnt[b * NTAB + ul[b * LL + tid]], 1);
}

// ---------------------------------------------------------------------------
// D_t = exp(root_t) + sum_{v in cand values} |Cv|*m_v*exp(sum sc) + sum_{s!=t} exp(span)
// Barrier-free: 256-thr block = 4 waves, each wave owns 4 rows.
// Link part: 16-lane slot per row, in-wave dedup of candidate values by shuffle,
// multiplicity from cnt table (replaces the 256-link scan).
__global__ __launch_bounds__(256) void kD(const float* __restrict__ scores,
                                          const int*   __restrict__ cand,
                                          const int*   __restrict__ cnt,
                                          float* __restrict__ invD,
                                          float* __restrict__ logD) {
    int blk  = blockIdx.x;                 // 1024 blocks: b*64 + chunk
    int b    = blk >> 6;
    int t0   = (blk & 63) << 4;            // 16 rows per block
    int lane = threadIdx.x & 63;
    int w    = threadIdx.x >> 6;           // wave 0..3
    int tw0  = t0 + w * 4;                 // this wave's first row

    // ---- link contributions for this wave's 4 rows ----
    int slot = lane >> 4;                  // which of the 4 rows
    int c    = lane & 15;                  // candidate index
    int t    = tw0 + slot;
    size_t bt = (size_t)b * SS + t;
    int   v   = cand[bt * CC + c];
    float scc = scores[bt * SCW + 1 + c];
    int   g = 0; float ssum = 0.0f; bool leader = true;
    int base16 = lane & 0x30;
#pragma unroll
    for (int j = 0; j < 16; ++j) {
        int   vj = __shfl(v,   base16 + j, 64);
        float sj = __shfl(scc, base16 + j, 64);
        bool  eq = (vj == v);
        g    += eq ? 1 : 0;
        ssum += eq ? sj : 0.0f;
        if (eq && j < c) leader = false;   // lowest-index holder of v is leader
    }
    float lc = 0.0f;
    int m = cnt[b * NTAB + v];
    if (leader && m) lc = (float)(g * m) * expf(ssum);
#pragma unroll
    for (int o = 8; o > 0; o >>= 1) lc += __shfl_xor(lc, o, 64);  // within 16-lane slot

    // ---- span rows: full-wave coalesced reads + shuffle reduce ----
#pragma unroll
    for (int r = 0; r < 4; ++r) {
        int tr = tw0 + r;
        const float* rp = scores + ((size_t)b * SS + tr) * SCW;
        float acc = 0.0f;
#pragma unroll
        for (int q = 0; q < 16; ++q) {
            int s = q * 64 + lane;
            float vv = rp[1 + CC + s];
            acc += (s != tr) ? expf(vv) : 0.0f;
        }
#pragma unroll
        for (int o = 32; o > 0; o >>= 1) acc += __shfl_xor(acc, o, 64);
        float lsum = __shfl(lc, r * 16, 64);    // link sum for row r
        if (lane == 0) {
            float Dv = acc + lsum + expf(rp[0]);
            invD[(size_t)b * SS + tr] = 1.0f / Dv;
            logD[(size_t)b * SS + tr] = logf(Dv);
        }
    }
}

// ---------------------------------------------------------------------------
// tr(R^2) = sum_{s != t} exp(sc[b,t,17+s] + sc[b,s,17+t]) * invD_t * invD_s
// symmetric: only si <= ti tiles, off-diagonal doubled; partials -> part (no atomics)
__global__ __launch_bounds__(256) void kTr2(const float* __restrict__ scores,
                                            const float* __restrict__ invD,
                                            float* __restrict__ part) {
    int si = blockIdx.x, ti = blockIdx.y, b = blockIdx.z;
    int pidx = (b * NT + ti) * NT + si;
    int tid  = threadIdx.x;
    if (si > ti) {
        if (tid == 0) part[pidx] = 0.0f;
        return;
    }
    int s0 = si * 64, t0 = ti * 64;
    const float* sb = scores + (size_t)b * SS * SCW;
    __shared__ float T2t[64][65];
    __shared__ float red[16];
    int lane = tid & 63;
    int row4 = tid >> 6;

#pragma unroll
    for (int r = 0; r < 16; ++r) {
        int j = r * 4 + row4;
        T2t[lane][j] = sb[(size_t)(s0 + j) * SCW + 1 + CC + t0 + lane];
    }
    __syncthreads();

    float ivs = invD[b * SS + s0 + lane];
    float acc = 0.0f;
#pragma unroll
    for (int r = 0; r < 16; ++r) {
        int i  = r * 4 + row4;
        int tg = t0 + i;
        float ivt = invD[b * SS + tg];
        float a = sb[(size_t)tg * SCW + 1 + CC + s0 + lane];
        float bt2 = T2t[i][lane];
        if (tg != s0 + lane) acc += expf(a + bt2) * ivt * ivs;
    }
    float tot = blockReduceSum(acc, red);
    if (tid == 0) part[pidx] = (si == ti) ? tot : 2.0f * tot;
}

// ---------------------------------------------------------------------------
// Partial matvec: x[b][s] += sum_{t in chunk, t != s} exp(sc[b,t,17+s]) * zin[b][t]
__global__ __launch_bounds__(256) void kMVp(const float* __restrict__ scores,
                                            const float* __restrict__ zin,
                                            float* __restrict__ xout) {
    int b   = blockIdx.y;
    int t0  = blockIdx.x * TCH;
    int tid = threadIdx.x;
    __shared__ float zl[TCH];
    if (tid < TCH) zl[tid] = zin[b * SS + t0 + tid];
    __syncthreads();

    float acc0 = 0.0f, acc1 = 0.0f, acc2 = 0.0f, acc3 = 0.0f;
    const float* base = scores + (size_t)(b * SS + t0) * SCW + 1 + CC;
#pragma unroll
    for (int r = 0; r < TCH; ++r) {
        const float* rp = base + (size_t)r * SCW;
        float z = zl[r];
        int   t = t0 + r;
        float v0 = rp[tid];
        float v1 = rp[tid + 256];
        float v2 = rp[tid + 512];
        float v3 = rp[tid + 768];
        acc0 += (t != tid)       ? expf(v0) * z : 0.0f;
        acc1 += (t != tid + 256) ? expf(v1) * z : 0.0f;
        acc2 += (t != tid + 512) ? expf(v2) * z : 0.0f;
        acc3 += (t != tid + 768) ? expf(v3) * z : 0.0f;
    }
    float* xo = xout + b * SS;
    atomicAdd(&xo[tid],       acc0);
    atomicAdd(&xo[tid + 256], acc1);
    atomicAdd(&xo[tid + 512], acc2);
    atomicAdd(&xo[tid + 768], acc3);
}

// ---------------------------------------------------------------------------
// z = x * invD elementwise; optionally re-zero the next accumulation buffer
__global__ __launch_bounds__(256) void kZ(const float* __restrict__ x,
                                          const float* __restrict__ invD,
                                          float* __restrict__ z,
                                          float* __restrict__ zeroBuf) {
    int i = blockIdx.x * 256 + threadIdx.x;   // grid = BB*SS/256 blocks
    z[i] = x[i] * invD[i];
    if (zeroBuf) zeroBuf[i] = 0.0f;
}

// ---------------------------------------------------------------------------
// Stage 1: one block per batch. d34, d33, sum(logD), tr2 partial-reduce, then
// bres[b] = sum_t logD + log(1-lam) + lam - 0.5*(tr2 - lam^2)
__global__ __launch_bounds__(256) void kFinA(const float* __restrict__ x3,
                                             const float* __restrict__ x4,
                                             const float* __restrict__ logD,
                                             const float* __restrict__ part,
                                             float* __restrict__ bres) {
    int b = blockIdx.x;
    int tid = threadIdx.x;
    __shared__ float red[16];
    float pd34 = 0.0f, pd33 = 0.0f, pslg = 0.0f;
#pragma unroll
    for (int r = 0; r < 4; ++r) {
        int i = b * SS + r * 256 + tid;
        float a = x3[i], c = x4[i], lg = logD[i];
        pd34 += a * c; pd33 += a * a; pslg += lg;
    }
    float pv = part[b * NT * NT + tid];          // blockDim == NT*NT == 256
    float d34 = blockReduceSum(pd34, red);
    float d33 = blockReduceSum(pd33, red);
    float slg = blockReduceSum(pslg, red);
    float t2  = blockReduceSum(pv, red);
    if (tid == 0) {
        float lam = d34 / d33;
        bres[b] = slg + log1pf(-lam) + lam - 0.5f * (t2 - lam * lam);
    }
}

// Stage 2: one wave reduces the 16 per-batch results
__global__ void kFinB(const float* __restrict__ bres, float* __restrict__ out) {
    int lane = threadIdx.x;                      // blockDim == 64
    float v = (lane < BB) ? bres[lane] : 0.0f;
#pragma unroll
    for (int o = 32; o > 0; o >>= 1) v += __shfl_xor(v, o, 64);
    if (lane == 0) out[0] = v / (float)BB;
}

// ---------------------------------------------------------------------------
extern "C" void kernel_launch(void* const* d_in, const int* in_sizes, int n_in,
                              void* d_out, int out_size, void* d_ws, size_t ws_size,
                              hipStream_t stream) {
    const float* scores = (const float*)d_in[0];
    const int*   cand   = (const int*)d_in[1];
    const int*   ul     = (const int*)d_in[2];
    float* out = (float*)d_out;

    float* ws   = (float*)d_ws;
    float* invD = ws;                   // BB*SS
    float* logD = invD + BB * SS;       // BB*SS
    float* xA   = logD + BB * SS;       // BB*SS  (x1, then x3)
    float* xB   = xA   + BB * SS;       // BB*SS  (x2, then x4)
    float* cntF = xB   + BB * SS;       // BB*NTAB ints (zeroed as floats)
    float* z    = cntF + BB * NTAB;     // BB*SS  (current z vector)
    float* part = z    + BB * SS;       // BB*NT*NT (kTr2 partials)
    float* bres = part + BB * NT * NT;  // BB
    int*   cnt  = (int*)cntF;

    // zero xA, xB, cnt in one contiguous sweep
    int nz = 2 * BB * SS + BB * NTAB;
    kInit<<<dim3((nz + 255) / 256), dim3(256), 0, stream>>>(xA, nz);
    kCount<<<dim3(BB), dim3(LL), 0, stream>>>(ul, cnt);

    kD<<<dim3(BB * SS / 16), dim3(256), 0, stream>>>(scores, cand, cnt, invD, logD);
    kTr2<<<dim3(NT, NT, BB), dim3(256), 0, stream>>>(scores, invD, part);

    // power iteration: x0 = ones  =>  z0 = invD
    dim3 mvGrid(NCH, BB);
    kMVp<<<mvGrid, dim3(256), 0, stream>>>(scores, invD, xA);            // x1 -> xA
    kZ<<<dim3(BB * SS / 256), dim3(256), 0, stream>>>(xA, invD, z, (float*)nullptr);
    kMVp<<<mvGrid, dim3(256), 0, stream>>>(scores, z, xB);               // x2 -> xB
    kZ<<<dim3(BB * SS / 256), dim3(256), 0, stream>>>(xB, invD, z, xA);  // zero xA for x3
    kMVp<<<mvGrid, dim3(256), 0, stream>>>(scores, z, xA);               // x3 -> xA
    kZ<<<dim3(BB * SS / 256), dim3(256), 0, stream>>>(xA, invD, z, xB);  // zero xB for x4
    kMVp<<<mvGrid, dim3(256), 0, stream>>>(scores, z, xB);               // x4 -> xB

    kFinA<<<dim3(BB), dim3(256), 0, stream>>>(xA, xB, logD, part, bres);
    kFinB<<<dim3(1), dim3(64), 0, stream>>>(bres, out);
}

// Round 4
// 117.934 us; speedup vs baseline: 3.9600x; 1.1698x over previous
//
#include <hip/hip_runtime.h>
#include <math.h>

// Problem constants (fixed by setup_inputs)
#define BB  16      // batch
#define SS  1024    // spans
#define CC  16      // candidates per span
#define LL  256     // unique links
#define SCW 1041    // 1 + CC + SS  (scores row width)
#define NTAB 5000   // candidate/link id space

#define TCH 16              // t-rows per kMVp chunk
#define NCH (SS / TCH)      // 64 chunks -> 64*16 = 1024 blocks
#define NT  (SS / 64)       // 16 tiles per axis in kTr2

// ---------------------------------------------------------------------------
// block-wide sum reduction (blockDim multiple of 64, <=1024), lds >= 16 floats
__device__ __forceinline__ float blockReduceSum(float v, float* lds) {
#pragma unroll
    for (int o = 32; o > 0; o >>= 1) v += __shfl_down(v, o, 64);
    int lane = threadIdx.x & 63;
    int wid  = threadIdx.x >> 6;
    int nw   = blockDim.x >> 6;
    if (lane == 0) lds[wid] = v;
    __syncthreads();
    v = (threadIdx.x < nw) ? lds[threadIdx.x] : 0.0f;
    if (wid == 0) {
#pragma unroll
        for (int o = 8; o > 0; o >>= 1) v += __shfl_down(v, o, 64);
        if (lane == 0) lds[0] = v;
    }
    __syncthreads();
    v = lds[0];
    __syncthreads();
    return v;
}

// ---------------------------------------------------------------------------
// zero n contiguous floats (also used to zero the int count table: 0.0f == 0)
__global__ void kInit(float* p, int n) {
    int i = blockIdx.x * blockDim.x + threadIdx.x;
    if (i < n) p[i] = 0.0f;
}

// ---------------------------------------------------------------------------
// per-batch link-id multiplicity table: cnt[b][id] = #occurrences in unique_links
__global__ __launch_bounds__(256) void kCount(const int* __restrict__ ul,
                                              int* __restrict__ cnt) {
    int b = blockIdx.x;
    int tid = threadIdx.x;                 // blockDim == LL == 256
    atomicAdd(&cnt[b * NTAB + ul[b * LL + tid]], 1);
}

// ---------------------------------------------------------------------------
// D_t = exp(root_t) + sum_{v in cand values} |Cv|*m_v*exp(sum sc) + sum_{s!=t} exp(span)
// ONE WAVE PER ROW (16K waves for TLP), barrier-free, LDS-free.
// Link part: lanes 0..15 hold the 16 candidates; in-wave dedup by shuffle;
// leader lanes fold lc into acc so a single 64-lane butterfly reduces all.
__global__ __launch_bounds__(256) void kD(const float* __restrict__ scores,
                                          const int*   __restrict__ cand,
                                          const int*   __restrict__ cnt,
                                          float* __restrict__ invD,
                                          float* __restrict__ logD) {
    int blk  = blockIdx.x;                 // 4096 blocks: b*256 + chunk-of-4
    int b    = blk >> 8;
    int lane = threadIdx.x & 63;
    int w    = threadIdx.x >> 6;           // wave 0..3 -> row
    int t    = ((blk & 255) << 2) + w;
    size_t bt = (size_t)b * SS + t;
    const float* rp = scores + bt * SCW;

    // issue all global loads up front; latency hides under the dedup loop
    float rt = rp[0];
    float xv[16];
#pragma unroll
    for (int q = 0; q < 16; ++q) xv[q] = rp[1 + CC + q * 64 + lane];

    int   c = lane & 15;
    int   v = -1 - lane;                   // unique non-id for lanes >= 16
    float scc = 0.0f;
    if (lane < 16) { v = cand[bt * CC + c]; scc = rp[1 + c]; }
    int m = (lane < 16) ? cnt[b * NTAB + v] : 0;

    int g = 0; float ssum = 0.0f; bool leader = (lane < 16);
#pragma unroll
    for (int j = 0; j < 16; ++j) {
        int   vj = __shfl(v,   j, 64);
        float sj = __shfl(scc, j, 64);
        bool  eq = (vj == v);
        g    += eq ? 1 : 0;
        ssum += eq ? sj : 0.0f;
        if (eq && j < c) leader = false;   // lowest-index holder of v leads
    }

    float acc = (leader && m) ? (float)(g * m) * expf(ssum) : 0.0f;
#pragma unroll
    for (int q = 0; q < 16; ++q) {
        int s = q * 64 + lane;
        acc += (s != t) ? expf(xv[q]) : 0.0f;
    }
#pragma unroll
    for (int o = 32; o > 0; o >>= 1) acc += __shfl_xor(acc, o, 64);
    if (lane == 0) {
        float Dv = acc + expf(rt);
        invD[bt] = 1.0f / Dv;
        logD[bt] = logf(Dv);
    }
}

// ---------------------------------------------------------------------------
// tr(R^2) = sum_{s != t} exp(sc[b,t,17+s] + sc[b,s,17+t]) * invD_t * invD_s
// symmetric: only si <= ti tiles, off-diagonal doubled; partials -> part (no atomics)
__global__ __launch_bounds__(256) void kTr2(const float* __restrict__ scores,
                                            const float* __restrict__ invD,
                                            float* __restrict__ part) {
    int si = blockIdx.x, ti = blockIdx.y, b = blockIdx.z;
    int pidx = (b * NT + ti) * NT + si;
    int tid  = threadIdx.x;
    if (si > ti) {
        if (tid == 0) part[pidx] = 0.0f;
        return;
    }
    int s0 = si * 64, t0 = ti * 64;
    const float* sb = scores + (size_t)b * SS * SCW;
    __shared__ float T2t[64][65];
    __shared__ float red[16];
    int lane = tid & 63;
    int row4 = tid >> 6;

#pragma unroll
    for (int r = 0; r < 16; ++r) {
        int j = r * 4 + row4;
        T2t[lane][j] = sb[(size_t)(s0 + j) * SCW + 1 + CC + t0 + lane];
    }
    __syncthreads();

    float ivs = invD[b * SS + s0 + lane];
    float acc = 0.0f;
#pragma unroll
    for (int r = 0; r < 16; ++r) {
        int i  = r * 4 + row4;
        int tg = t0 + i;
        float ivt = invD[b * SS + tg];
        float a = sb[(size_t)tg * SCW + 1 + CC + s0 + lane];
        float bt2 = T2t[i][lane];
        if (tg != s0 + lane) acc += expf(a + bt2) * ivt * ivs;
    }
    float tot = blockReduceSum(acc, red);
    if (tid == 0) part[pidx] = (si == ti) ? tot : 2.0f * tot;
}

// ---------------------------------------------------------------------------
// Partial matvec: x[b][s] += sum_{t in chunk, t != s} exp(sc[b,t,17+s]) * z_t
// where z_t = xin[t]*invD[t] (xin==NULL => z = invD, the x0=ones case).
// Block (t0,b) is the ONLY reader of xin[b][t0..t0+16): it may zero that
// slice (zeroSlice==xin) after staging, readying the buffer for reuse.
__global__ __launch_bounds__(256) void kMVp(const float* __restrict__ scores,
                                            const float* __restrict__ xin,
                                            const float* __restrict__ invD,
                                            float* __restrict__ xout,
                                            float* __restrict__ zeroSlice) {
    int b   = blockIdx.y;
    int t0  = blockIdx.x * TCH;
    int tid = threadIdx.x;
    __shared__ float zl[TCH];
    if (tid < TCH) {
        int i = b * SS + t0 + tid;
        float zz = invD[i];
        if (xin) zz *= xin[i];
        zl[tid] = zz;
    }
    __syncthreads();
    if (zeroSlice && tid < TCH) zeroSlice[b * SS + t0 + tid] = 0.0f;

    float acc0 = 0.0f, acc1 = 0.0f, acc2 = 0.0f, acc3 = 0.0f;
    const float* base = scores + (size_t)(b * SS + t0) * SCW + 1 + CC;
#pragma unroll
    for (int r = 0; r < TCH; ++r) {
        const float* rp = base + (size_t)r * SCW;
        float z = zl[r];
        int   t = t0 + r;
        float v0 = rp[tid];
        float v1 = rp[tid + 256];
        float v2 = rp[tid + 512];
        float v3 = rp[tid + 768];
        acc0 += (t != tid)       ? expf(v0) * z : 0.0f;
        acc1 += (t != tid + 256) ? expf(v1) * z : 0.0f;
        acc2 += (t != tid + 512) ? expf(v2) * z : 0.0f;
        acc3 += (t != tid + 768) ? expf(v3) * z : 0.0f;
    }
    float* xo = xout + b * SS;
    atomicAdd(&xo[tid],       acc0);
    atomicAdd(&xo[tid + 256], acc1);
    atomicAdd(&xo[tid + 512], acc2);
    atomicAdd(&xo[tid + 768], acc3);
}

// ---------------------------------------------------------------------------
// Stage 1: one block per batch. d34, d33, sum(logD), tr2 partial-reduce, then
// bres[b] = sum_t logD + log(1-lam) + lam - 0.5*(tr2 - lam^2)
__global__ __launch_bounds__(256) void kFinA(const float* __restrict__ x3,
                                             const float* __restrict__ x4,
                                             const float* __restrict__ logD,
                                             const float* __restrict__ part,
                                             float* __restrict__ bres) {
    int b = blockIdx.x;
    int tid = threadIdx.x;
    __shared__ float red[16];
    float pd34 = 0.0f, pd33 = 0.0f, pslg = 0.0f;
#pragma unroll
    for (int r = 0; r < 4; ++r) {
        int i = b * SS + r * 256 + tid;
        float a = x3[i], c = x4[i], lg = logD[i];
        pd34 += a * c; pd33 += a * a; pslg += lg;
    }
    float pv = part[b * NT * NT + tid];          // blockDim == NT*NT == 256
    float d34 = blockReduceSum(pd34, red);
    float d33 = blockReduceSum(pd33, red);
    float slg = blockReduceSum(pslg, red);
    float t2  = blockReduceSum(pv, red);
    if (tid == 0) {
        float lam = d34 / d33;
        bres[b] = slg + log1pf(-lam) + lam - 0.5f * (t2 - lam * lam);
    }
}

// Stage 2: one wave reduces the 16 per-batch results
__global__ void kFinB(const float* __restrict__ bres, float* __restrict__ out) {
    int lane = threadIdx.x;                      // blockDim == 64
    float v = (lane < BB) ? bres[lane] : 0.0f;
#pragma unroll
    for (int o = 32; o > 0; o >>= 1) v += __shfl_xor(v, o, 64);
    if (lane == 0) out[0] = v / (float)BB;
}

// ---------------------------------------------------------------------------
extern "C" void kernel_launch(void* const* d_in, const int* in_sizes, int n_in,
                              void* d_out, int out_size, void* d_ws, size_t ws_size,
                              hipStream_t stream) {
    const float* scores = (const float*)d_in[0];
    const int*   cand   = (const int*)d_in[1];
    const int*   ul     = (const int*)d_in[2];
    float* out = (float*)d_out;

    float* ws   = (float*)d_ws;
    float* invD = ws;                   // BB*SS
    float* logD = invD + BB * SS;       // BB*SS
    float* xA   = logD + BB * SS;       // BB*SS  (x1, then x3)
    float* xB   = xA   + BB * SS;       // BB*SS  (x2, then x4)
    float* cntF = xB   + BB * SS;       // BB*NTAB ints (zeroed as floats)
    float* part = cntF + BB * NTAB;     // BB*NT*NT (kTr2 partials)
    float* bres = part + BB * NT * NT;  // BB
    int*   cnt  = (int*)cntF;

    // zero xA, xB, cnt in one contiguous sweep
    int nz = 2 * BB * SS + BB * NTAB;
    kInit<<<dim3((nz + 255) / 256), dim3(256), 0, stream>>>(xA, nz);
    kCount<<<dim3(BB), dim3(LL), 0, stream>>>(ul, cnt);

    kD<<<dim3(BB * SS / 4), dim3(256), 0, stream>>>(scores, cand, cnt, invD, logD);
    kTr2<<<dim3(NT, NT, BB), dim3(256), 0, stream>>>(scores, invD, part);

    // power iteration: x0 = ones => z0 = invD.  z folded into kMVp's zl load;
    // buffer re-zeroing folded into the kMVp that last READS the buffer.
    dim3 mvGrid(NCH, BB);
    kMVp<<<mvGrid, dim3(256), 0, stream>>>(scores, (const float*)nullptr, invD, xA, (float*)nullptr); // x1 -> xA
    kMVp<<<mvGrid, dim3(256), 0, stream>>>(scores, xA, invD, xB, xA);                 // x2 -> xB, zero xA
    kMVp<<<mvGrid, dim3(256), 0, stream>>>(scores, xB, invD, xA, xB);                 // x3 -> xA, zero xB
    kMVp<<<mvGrid, dim3(256), 0, stream>>>(scores, xA, invD, xB, (float*)nullptr);    // x4 -> xB (keep xA = x3)

    kFinA<<<dim3(BB), dim3(256), 0, stream>>>(xA, xB, logD, part, bres);
    kFinB<<<dim3(1), dim3(64), 0, stream>>>(bres, out);
}

// Round 5
// 116.840 us; speedup vs baseline: 3.9971x; 1.0094x over previous
//
#include <hip/hip_runtime.h>
#include <math.h>

// Problem constants (fixed by setup_inputs)
#define BB  16      // batch
#define SS  1024    // spans
#define CC  16      // candidates per span
#define LL  256     // unique links
#define SCW 1041    // 1 + CC + SS  (scores row width)
#define NTAB 5000   // candidate/link id space

#define TCH 16              // t-rows per matvec chunk
#define NCH (SS / TCH)      // 64 chunks per batch
#define NT  (SS / 64)       // 16 tiles per axis in tr2
#define NTRI (NT * (NT + 1) / 2)   // 136 upper-tri tiles per batch
#define MVBLKS (NCH * BB)   // 1024 matvec blocks

// ---------------------------------------------------------------------------
// block-wide sum reduction (blockDim multiple of 64, <=1024), lds >= 16 floats
__device__ __forceinline__ float blockReduceSum(float v, float* lds) {
#pragma unroll
    for (int o = 32; o > 0; o >>= 1) v += __shfl_down(v, o, 64);
    int lane = threadIdx.x & 63;
    int wid  = threadIdx.x >> 6;
    int nw   = blockDim.x >> 6;
    if (lane == 0) lds[wid] = v;
    __syncthreads();
    v = (threadIdx.x < nw) ? lds[threadIdx.x] : 0.0f;
    if (wid == 0) {
#pragma unroll
        for (int o = 8; o > 0; o >>= 1) v += __shfl_down(v, o, 64);
        if (lane == 0) lds[0] = v;
    }
    __syncthreads();
    v = lds[0];
    __syncthreads();
    return v;
}

// ---------------------------------------------------------------------------
// Per-batch setup, fused: block b zeroes ITS OWN cnt slice, x slices, part
// slice (no cross-block ordering needed), then counts link multiplicities.
__global__ __launch_bounds__(256) void kCnt(const int* __restrict__ ul,
                                            int*   __restrict__ cnt,
                                            float* __restrict__ xz,    // xA..xB, 2*SS per batch
                                            float* __restrict__ part,  // NT*NT per batch
                                            int*   __restrict__ fincnt) {
    int b = blockIdx.x, tid = threadIdx.x;
    int* cb = cnt + b * NTAB;
    for (int i = tid; i < NTAB; i += 256) cb[i] = 0;
    float* xb = xz + b * 2 * SS;
#pragma unroll
    for (int i = 0; i < 2 * SS / 256; ++i) xb[tid + i * 256] = 0.0f;
    part[b * NT * NT + tid] = 0.0f;            // blockDim == NT*NT == 256
    if (b == 0 && tid == 0) *fincnt = 0;
    __syncthreads();
    atomicAdd(&cb[ul[b * LL + tid]], 1);
}

// ---------------------------------------------------------------------------
// D_t = exp(root_t) + sum_{v in cand values} |Cv|*m_v*exp(sum sc) + sum_{s!=t} exp(span)
// ONE WAVE PER ROW (16K waves for TLP), barrier-free, LDS-free.
__global__ __launch_bounds__(256) void kD(const float* __restrict__ scores,
                                          const int*   __restrict__ cand,
                                          const int*   __restrict__ cnt,
                                          float* __restrict__ invD,
                                          float* __restrict__ logD) {
    int blk  = blockIdx.x;                 // 4096 blocks: b*256 + chunk-of-4
    int b    = blk >> 8;
    int lane = threadIdx.x & 63;
    int w    = threadIdx.x >> 6;           // wave 0..3 -> row
    int t    = ((blk & 255) << 2) + w;
    size_t bt = (size_t)b * SS + t;
    const float* rp = scores + bt * SCW;

    // issue all global loads up front; latency hides under the dedup loop
    float rt = rp[0];
    float xv[16];
#pragma unroll
    for (int q = 0; q < 16; ++q) xv[q] = rp[1 + CC + q * 64 + lane];

    int   c = lane & 15;
    int   v = -1 - lane;                   // unique non-id for lanes >= 16
    float scc = 0.0f;
    if (lane < 16) { v = cand[bt * CC + c]; scc = rp[1 + c]; }
    int m = (lane < 16) ? cnt[b * NTAB + v] : 0;

    int g = 0; float ssum = 0.0f; bool leader = (lane < 16);
#pragma unroll
    for (int j = 0; j < 16; ++j) {
        int   vj = __shfl(v,   j, 64);
        float sj = __shfl(scc, j, 64);
        bool  eq = (vj == v);
        g    += eq ? 1 : 0;
        ssum += eq ? sj : 0.0f;
        if (eq && j < c) leader = false;   // lowest-index holder of v leads
    }

    float acc = (leader && m) ? (float)(g * m) * expf(ssum) : 0.0f;
#pragma unroll
    for (int q = 0; q < 16; ++q) {
        int s = q * 64 + lane;
        acc += (s != t) ? expf(xv[q]) : 0.0f;
    }
#pragma unroll
    for (int o = 32; o > 0; o >>= 1) acc += __shfl_xor(acc, o, 64);
    if (lane == 0) {
        float Dv = acc + expf(rt);
        invD[bt] = 1.0f / Dv;
        logD[bt] = logf(Dv);
    }
}

// ---------------------------------------------------------------------------
// shared matvec body: x[b][s] += sum_{t in chunk, t != s} exp(sc[b,t,17+s]) * z_t
// z_t = xin[t]*invD[t] (xin==NULL => z = invD). Block (t0,b) is the only
// reader of xin[b][t0..t0+16): it may zero that slice after the barrier.
__device__ __forceinline__ void mvBody(const float* __restrict__ scores,
                                       const float* __restrict__ xin,
                                       const float* __restrict__ invD,
                                       float* __restrict__ xout,
                                       float* __restrict__ zeroSlice,
                                       int b, int t0, float* zl) {
    int tid = threadIdx.x;
    if (tid < TCH) {
        int i = b * SS + t0 + tid;
        float zz = invD[i];
        if (xin) zz *= xin[i];
        zl[tid] = zz;
    }
    __syncthreads();
    if (zeroSlice && tid < TCH) zeroSlice[b * SS + t0 + tid] = 0.0f;

    float acc0 = 0.0f, acc1 = 0.0f, acc2 = 0.0f, acc3 = 0.0f;
    const float* base = scores + (size_t)(b * SS + t0) * SCW + 1 + CC;
#pragma unroll
    for (int r = 0; r < TCH; ++r) {
        const float* rp = base + (size_t)r * SCW;
        float z = zl[r];
        int   t = t0 + r;
        float v0 = rp[tid];
        float v1 = rp[tid + 256];
        float v2 = rp[tid + 512];
        float v3 = rp[tid + 768];
        acc0 += (t != tid)       ? expf(v0) * z : 0.0f;
        acc1 += (t != tid + 256) ? expf(v1) * z : 0.0f;
        acc2 += (t != tid + 512) ? expf(v2) * z : 0.0f;
        acc3 += (t != tid + 768) ? expf(v3) * z : 0.0f;
    }
    float* xo = xout + b * SS;
    atomicAdd(&xo[tid],       acc0);
    atomicAdd(&xo[tid + 256], acc1);
    atomicAdd(&xo[tid + 512], acc2);
    atomicAdd(&xo[tid + 768], acc3);
}

// standalone matvec (mv2..mv4), 2D grid (NCH, BB)
__global__ __launch_bounds__(256) void kMVp(const float* __restrict__ scores,
                                            const float* __restrict__ xin,
                                            const float* __restrict__ invD,
                                            float* __restrict__ xout,
                                            float* __restrict__ zeroSlice) {
    __shared__ float zl[TCH];
    mvBody(scores, xin, invD, xout, zeroSlice, blockIdx.y, blockIdx.x * TCH, zl);
}

// ---------------------------------------------------------------------------
// FUSED dispatch: mv1 (x1 = W'invD, bid < MVBLKS) runs concurrently with the
// upper-triangular tr2 tiles (independent work, both need only invD).
// tr(R^2) = sum_{s != t} exp(sc[b,t,17+s] + sc[b,s,17+t]) * invD_t * invD_s;
// off-diagonal tiles doubled; per-tile partial -> part (zeros pre-set by kCnt,
// keeping kFinA's 256-wide reduction tree bit-identical).
__global__ __launch_bounds__(256) void kTrMV1(const float* __restrict__ scores,
                                              const float* __restrict__ invD,
                                              float* __restrict__ part,
                                              float* __restrict__ xout) {
    __shared__ float T2t[64][65];
    __shared__ float red[16];
    __shared__ float zl[TCH];
    int bid = blockIdx.x;
    int tid = threadIdx.x;

    if (bid < MVBLKS) {    // matvec role: x1 -> xout (z = invD, x0 = ones)
        int b  = bid >> 6;
        int t0 = (bid & 63) * TCH;
        mvBody(scores, (const float*)nullptr, invD, xout, (float*)nullptr, b, t0, zl);
        return;
    }

    // tr2 role: decode linear upper-triangular tile index
    int idx = bid - MVBLKS;
    int b   = idx / NTRI;
    int r   = idx - b * NTRI;
    int ti  = (int)((sqrtf(8.0f * (float)r + 1.0f) - 1.0f) * 0.5f);
    while ((ti + 1) * (ti + 2) / 2 <= r) ++ti;   // float-safety correction
    while (ti * (ti + 1) / 2 > r) --ti;
    int si  = r - ti * (ti + 1) / 2;             // si <= ti

    int s0 = si * 64, t0 = ti * 64;
    const float* sb = scores + (size_t)b * SS * SCW;
    int lane = tid & 63;
    int row4 = tid >> 6;

    // load mirrored tile: T2t[i][j] = sc(b, s0+j, 17 + t0 + i)
#pragma unroll
    for (int q = 0; q < 16; ++q) {
        int j = q * 4 + row4;
        T2t[lane][j] = sb[(size_t)(s0 + j) * SCW + 1 + CC + t0 + lane];
    }
    __syncthreads();

    float ivs = invD[b * SS + s0 + lane];
    float acc = 0.0f;
#pragma unroll
    for (int q = 0; q < 16; ++q) {
        int i  = q * 4 + row4;
        int tg = t0 + i;
        float ivt = invD[b * SS + tg];
        float a = sb[(size_t)tg * SCW + 1 + CC + s0 + lane];
        float bt2 = T2t[i][lane];
        if (tg != s0 + lane) acc += expf(a + bt2) * ivt * ivs;
    }
    float tot = blockReduceSum(acc, red);
    if (tid == 0) part[(b * NT + ti) * NT + si] = (si == ti) ? tot : 2.0f * tot;
}

// ---------------------------------------------------------------------------
// One block per batch: d34, d33, sum(logD), tr2 reduce, then
// bres[b] = sum_t logD + log(1-lam) + lam - 0.5*(tr2 - lam^2).
// Last finishing block reduces bres -> out (threadfence+counter pattern),
// replicating the old kFinB's 64-lane butterfly exactly (bit-identical).
__global__ __launch_bounds__(256) void kFinA(const float* __restrict__ x3,
                                             const float* __restrict__ x4,
                                             const float* __restrict__ logD,
                                             const float* __restrict__ part,
                                             float* __restrict__ bres,
                                             int*   __restrict__ fincnt,
                                             float* __restrict__ out) {
    int b = blockIdx.x;
    int tid = threadIdx.x;
    __shared__ float red[16];
    __shared__ int isLast;
    float pd34 = 0.0f, pd33 = 0.0f, pslg = 0.0f;
#pragma unroll
    for (int r = 0; r < 4; ++r) {
        int i = b * SS + r * 256 + tid;
        float a = x3[i], c = x4[i], lg = logD[i];
        pd34 += a * c; pd33 += a * a; pslg += lg;
    }
    float pv = part[b * NT * NT + tid];          // blockDim == NT*NT == 256
    float d34 = blockReduceSum(pd34, red);
    float d33 = blockReduceSum(pd33, red);
    float slg = blockReduceSum(pslg, red);
    float t2  = blockReduceSum(pv, red);
    if (tid == 0) {
        float lam = d34 / d33;
        bres[b] = slg + log1pf(-lam) + lam - 0.5f * (t2 - lam * lam);
    }
    __threadfence();
    if (tid == 0) isLast = (atomicAdd(fincnt, 1) == BB - 1);
    __syncthreads();
    if (isLast && tid < 64) {
        __threadfence();
        float v = (tid < BB) ? bres[tid] : 0.0f;
#pragma unroll
        for (int o = 32; o > 0; o >>= 1) v += __shfl_xor(v, o, 64);
        if (tid == 0) out[0] = v / (float)BB;
    }
}

// ---------------------------------------------------------------------------
extern "C" void kernel_launch(void* const* d_in, const int* in_sizes, int n_in,
                              void* d_out, int out_size, void* d_ws, size_t ws_size,
                              hipStream_t stream) {
    const float* scores = (const float*)d_in[0];
    const int*   cand   = (const int*)d_in[1];
    const int*   ul     = (const int*)d_in[2];
    float* out = (float*)d_out;

    float* ws   = (float*)d_ws;
    float* invD = ws;                   // BB*SS
    float* logD = invD + BB * SS;       // BB*SS
    float* xA   = logD + BB * SS;       // BB*SS  (x1, then x3)
    float* xB   = xA   + BB * SS;       // BB*SS  (x2, then x4)
    float* cntF = xB   + BB * SS;       // BB*NTAB ints
    float* part = cntF + BB * NTAB;     // BB*NT*NT (tr2 partials)
    float* bres = part + BB * NT * NT;  // BB
    int*   fincnt = (int*)(bres + 64);  // completion counter
    int*   cnt  = (int*)cntF;

    // 1: per-batch zero (cnt, xA/xB, part, fincnt) + link multiplicity count
    kCnt<<<dim3(BB), dim3(256), 0, stream>>>(ul, cnt, xA, part, fincnt);
    // 2: column sums D
    kD<<<dim3(BB * SS / 4), dim3(256), 0, stream>>>(scores, cand, cnt, invD, logD);
    // 3: tr(R^2) tiles FUSED with mv1 (independent given invD) -> overlap
    kTrMV1<<<dim3(MVBLKS + BB * NTRI), dim3(256), 0, stream>>>(scores, invD, part, xA);
    // 4-6: power iteration x2..x4 (z folded into zl load; re-zero folded into
    //      the pass that last reads the buffer)
    dim3 mvGrid(NCH, BB);
    kMVp<<<mvGrid, dim3(256), 0, stream>>>(scores, xA, invD, xB, xA);              // x2 -> xB, zero xA
    kMVp<<<mvGrid, dim3(256), 0, stream>>>(scores, xB, invD, xA, xB);              // x3 -> xA, zero xB
    kMVp<<<mvGrid, dim3(256), 0, stream>>>(scores, xA, invD, xB, (float*)nullptr); // x4 -> xB (keep xA)
    // 7: per-batch finish + last-block global reduce
    kFinA<<<dim3(BB), dim3(256), 0, stream>>>(xA, xB, logD, part, bres, fincnt, out);
}

// Round 7
// 85.515 us; speedup vs baseline: 5.4613x; 1.3663x over previous
//
#include <hip/hip_runtime.h>
#include <hip/hip_fp16.h>
#include <math.h>

// Problem constants (fixed by setup_inputs)
#define BB  16      // batch
#define SS  1024    // spans
#define CC  16      // candidates per span
#define LL  256     // unique links
#define SCW 1041    // 1 + CC + SS  (scores row width)
#define NTAB 5000   // candidate/link id space

#define TCH 16                    // t-rows per matvec chunk
#define NCH (SS / TCH)            // 64 chunks per batch
#define NT  (SS / 64)             // 16 tiles per axis in tr2
#define NTRI (NT * (NT + 1) / 2)  // 136 upper-tri tiles per batch

// ---------------------------------------------------------------------------
// block-wide sum reduction (blockDim multiple of 64, <=1024), lds >= 16 floats
__device__ __forceinline__ float blockReduceSum(float v, float* lds) {
#pragma unroll
    for (int o = 32; o > 0; o >>= 1) v += __shfl_down(v, o, 64);
    int lane = threadIdx.x & 63;
    int wid  = threadIdx.x >> 6;
    int nw   = blockDim.x >> 6;
    if (lane == 0) lds[wid] = v;
    __syncthreads();
    v = (threadIdx.x < nw) ? lds[threadIdx.x] : 0.0f;
    if (wid == 0) {
#pragma unroll
        for (int o = 8; o > 0; o >>= 1) v += __shfl_down(v, o, 64);
        if (lane == 0) lds[0] = v;
    }
    __syncthreads();
    v = lds[0];
    __syncthreads();
    return v;
}

// ---------------------------------------------------------------------------
// Per-batch setup: block b zeroes its own cnt slice, xA/xB slices, part slice;
// then counts link multiplicities.
__global__ __launch_bounds__(256) void kCnt(const int* __restrict__ ul,
                                            int*   __restrict__ cnt,
                                            float* __restrict__ xz,    // xA..xB, 2*SS per batch
                                            float* __restrict__ part,
                                            int*   __restrict__ fincnt) {
    int b = blockIdx.x, tid = threadIdx.x;
    int* cb = cnt + b * NTAB;
    for (int i = tid; i < NTAB; i += 256) cb[i] = 0;
    float* xb = xz + b * 2 * SS;
#pragma unroll
    for (int i = 0; i < 2 * SS / 256; ++i) xb[tid + i * 256] = 0.0f;
    part[b * NT * NT + tid] = 0.0f;            // blockDim == NT*NT == 256
    if (b == 0 && tid == 0) *fincnt = 0;
    __syncthreads();
    atomicAdd(&cb[ul[b * LL + tid]], 1);
}

// ---------------------------------------------------------------------------
// D_t = exp(root_t) + link term + sum_{s!=t} exp(span).  ONE WAVE PER ROW,
// barrier-free, LDS-free.  ALSO materializes Wh[t][s] = (half)exp(span score)
// with diagonal zeroed — the matvecs and tr2 then read 2B/elem and need no
// expf and no diag branch.  D itself stays fp32-exact (sums fp32 exps).
__global__ __launch_bounds__(256) void kD(const float* __restrict__ scores,
                                          const int*   __restrict__ cand,
                                          const int*   __restrict__ cnt,
                                          float* __restrict__ invD,
                                          float* __restrict__ logD,
                                          __half* __restrict__ Wh) {
    int blk  = blockIdx.x;                 // 4096 blocks: b*256 + chunk-of-4
    int b    = blk >> 8;
    int lane = threadIdx.x & 63;
    int w    = threadIdx.x >> 6;           // wave 0..3 -> row
    int t    = ((blk & 255) << 2) + w;
    size_t bt = (size_t)b * SS + t;
    const float* rp = scores + bt * SCW;

    // issue all global loads up front; latency hides under the dedup loop
    float rt = rp[0];
    float xv[16];
#pragma unroll
    for (int q = 0; q < 16; ++q) xv[q] = rp[1 + CC + q * 64 + lane];

    int   c = lane & 15;
    int   v = -1 - lane;                   // unique non-id for lanes >= 16
    float scc = 0.0f;
    if (lane < 16) { v = cand[bt * CC + c]; scc = rp[1 + c]; }
    int m = (lane < 16) ? cnt[b * NTAB + v] : 0;

    int g = 0; float ssum = 0.0f; bool leader = (lane < 16);
#pragma unroll
    for (int j = 0; j < 16; ++j) {
        int   vj = __shfl(v,   j, 64);
        float sj = __shfl(scc, j, 64);
        bool  eq = (vj == v);
        g    += eq ? 1 : 0;
        ssum += eq ? sj : 0.0f;
        if (eq && j < c) leader = false;   // lowest-index holder of v leads
    }

    float acc = (leader && m) ? (float)(g * m) * expf(ssum) : 0.0f;
    __half* wrow = Wh + bt * SS;
#pragma unroll
    for (int q = 0; q < 16; ++q) {
        int s = q * 64 + lane;
        float ev = (s != t) ? expf(xv[q]) : 0.0f;   // diag zeroed at source
        acc += ev;
        wrow[s] = __float2half(ev);
    }
#pragma unroll
    for (int o = 32; o > 0; o >>= 1) acc += __shfl_xor(acc, o, 64);
    if (lane == 0) {
        float Dv = acc + expf(rt);
        invD[bt] = 1.0f / Dv;
        logD[bt] = logf(Dv);
    }
}

// ---------------------------------------------------------------------------
// tr(R^2) = sum_{s,t} Wh[t][s]*Wh[s][t] * invD_t * invD_s  (diag zero in Wh)
// upper-triangular tiles only, off-diagonal doubled; partial -> part.
__global__ __launch_bounds__(256) void kTr2(const __half* __restrict__ Wh,
                                            const float* __restrict__ invD,
                                            float* __restrict__ part) {
    int idx = blockIdx.x;                  // BB * NTRI blocks
    int b   = idx / NTRI;
    int r   = idx - b * NTRI;
    int ti  = (int)((sqrtf(8.0f * (float)r + 1.0f) - 1.0f) * 0.5f);
    while ((ti + 1) * (ti + 2) / 2 <= r) ++ti;   // float-safety correction
    while (ti * (ti + 1) / 2 > r) --ti;
    int si  = r - ti * (ti + 1) / 2;             // si <= ti

    int s0 = si * 64, t0 = ti * 64;
    const __half* wb = Wh + (size_t)b * SS * SS;
    __shared__ float T2t[64][65];
    __shared__ float red[16];
    int tid  = threadIdx.x;
    int lane = tid & 63;
    int row4 = tid >> 6;

    // mirrored tile: T2t[i][j] = W(b, s0+j, t0+i)
#pragma unroll
    for (int q = 0; q < 16; ++q) {
        int j = q * 4 + row4;
        T2t[lane][j] = __half2float(wb[(size_t)(s0 + j) * SS + t0 + lane]);
    }
    __syncthreads();

    float ivs = invD[b * SS + s0 + lane];
    float acc = 0.0f;
#pragma unroll
    for (int q = 0; q < 16; ++q) {
        int i  = q * 4 + row4;
        int tg = t0 + i;
        float ivt = invD[b * SS + tg];
        float a   = __half2float(wb[(size_t)tg * SS + s0 + lane]);
        acc += a * T2t[i][lane] * ivt * ivs;     // diag products are 0 by construction
    }
    float tot = blockReduceSum(acc, red);
    if (tid == 0) part[(b * NT + ti) * NT + si] = (si == ti) ? tot : 2.0f * tot;
}

// ---------------------------------------------------------------------------
// Partial matvec on half W: x[b][s] += sum_t W[t][s] * z_t, z = xin*invD
// (xin==NULL => z = invD).  half2 loads: thread covers cols {2tid,2tid+1,
// 512+2tid,512+2tid+1}.  No diag branch (Wh diag is zero).
// Block (t0,b) is the only reader of xin[b][t0..t0+16): may zero that slice.
__global__ __launch_bounds__(256) void kMVh(const __half2* __restrict__ Wh2,
                                            const float* __restrict__ xin,
                                            const float* __restrict__ invD,
                                            float* __restrict__ xout,
                                            float* __restrict__ zeroSlice) {
    int b   = blockIdx.y;
    int t0  = blockIdx.x * TCH;
    int tid = threadIdx.x;
    __shared__ float zl[TCH];
    if (tid < TCH) {
        int i = b * SS + t0 + tid;
        float zz = invD[i];
        if (xin) zz *= xin[i];
        zl[tid] = zz;
    }
    __syncthreads();
    if (zeroSlice && tid < TCH) zeroSlice[b * SS + t0 + tid] = 0.0f;

    float a00 = 0.0f, a01 = 0.0f, a10 = 0.0f, a11 = 0.0f;
    const __half2* base = Wh2 + (size_t)(b * SS + t0) * (SS / 2);
#pragma unroll
    for (int r = 0; r < TCH; ++r) {
        const __half2* rp = base + (size_t)r * (SS / 2);
        float z = zl[r];
        float2 lo = __half22float2(rp[tid]);
        float2 hi = __half22float2(rp[tid + 256]);
        a00 += lo.x * z; a01 += lo.y * z;
        a10 += hi.x * z; a11 += hi.y * z;
    }
    float* xo = xout + b * SS;
    atomicAdd(&xo[2 * tid],           a00);
    atomicAdd(&xo[2 * tid + 1],       a01);
    atomicAdd(&xo[512 + 2 * tid],     a10);
    atomicAdd(&xo[512 + 2 * tid + 1], a11);
}

// ---------------------------------------------------------------------------
// One block per batch: d34, d33, sum(logD), tr2 reduce, per-batch loss;
// last finishing block reduces bres -> out (threadfence+counter pattern).
__global__ __launch_bounds__(256) void kFinA(const float* __restrict__ x3,
                                             const float* __restrict__ x4,
                                             const float* __restrict__ logD,
                                             const float* __restrict__ part,
                                             float* __restrict__ bres,
                                             int*   __restrict__ fincnt,
                                             float* __restrict__ out) {
    int b = blockIdx.x;
    int tid = threadIdx.x;
    __shared__ float red[16];
    __shared__ int isLast;
    float pd34 = 0.0f, pd33 = 0.0f, pslg = 0.0f;
#pragma unroll
    for (int r = 0; r < 4; ++r) {
        int i = b * SS + r * 256 + tid;
        float a = x3[i], c = x4[i], lg = logD[i];
        pd34 += a * c; pd33 += a * a; pslg += lg;
    }
    float pv = part[b * NT * NT + tid];          // blockDim == NT*NT == 256
    float d34 = blockReduceSum(pd34, red);
    float d33 = blockReduceSum(pd33, red);
    float slg = blockReduceSum(pslg, red);
    float t2  = blockReduceSum(pv, red);
    if (tid == 0) {
        float lam = d34 / d33;
        bres[b] = slg + log1pf(-lam) + lam - 0.5f * (t2 - lam * lam);
    }
    __threadfence();
    if (tid == 0) isLast = (atomicAdd(fincnt, 1) == BB - 1);
    __syncthreads();
    if (isLast && tid < 64) {
        __threadfence();
        float v = (tid < BB) ? bres[tid] : 0.0f;
#pragma unroll
        for (int o = 32; o > 0; o >>= 1) v += __shfl_xor(v, o, 64);
        if (tid == 0) out[0] = v / (float)BB;
    }
}

// ---------------------------------------------------------------------------
extern "C" void kernel_launch(void* const* d_in, const int* in_sizes, int n_in,
                              void* d_out, int out_size, void* d_ws, size_t ws_size,
                              hipStream_t stream) {
    const float* scores = (const float*)d_in[0];
    const int*   cand   = (const int*)d_in[1];
    const int*   ul     = (const int*)d_in[2];
    float* out = (float*)d_out;

    float* ws   = (float*)d_ws;
    float* invD = ws;                   // BB*SS
    float* logD = invD + BB * SS;       // BB*SS
    float* xA   = logD + BB * SS;       // BB*SS  (x1, then x3)
    float* xB   = xA   + BB * SS;       // BB*SS  (x2, then x4)
    float* cntF = xB   + BB * SS;       // BB*NTAB ints
    float* part = cntF + BB * NTAB;     // BB*NT*NT (tr2 partials)
    float* bres = part + BB * NT * NT;  // 64 (BB used)
    int*   fincnt = (int*)(bres + 64);  // completion counter
    float* whF  = bres + 80;            // half W: BB*SS*SS halfs = 8M floats
    int*   cnt  = (int*)cntF;
    __half* Wh  = (__half*)whF;

    // 1: per-batch zeroing (cnt, xA/xB, part, fincnt) + link multiplicities
    kCnt<<<dim3(BB), dim3(256), 0, stream>>>(ul, cnt, xA, part, fincnt);
    // 2: column sums D (fp32-exact) + materialize Wh = half(exp), diag zeroed
    kD<<<dim3(BB * SS / 4), dim3(256), 0, stream>>>(scores, cand, cnt, invD, logD, Wh);
    // 3: tr(R^2) upper-triangular tiles from Wh (no expf, no branch)
    kTr2<<<dim3(BB * NTRI), dim3(256), 0, stream>>>(Wh, invD, part);
    // 4-7: power iteration from Wh (x0 = ones => z0 = invD); re-zero folded in
    dim3 mvGrid(NCH, BB);
    kMVh<<<mvGrid, dim3(256), 0, stream>>>((const __half2*)Wh, (const float*)nullptr, invD, xA, (float*)nullptr); // x1
    kMVh<<<mvGrid, dim3(256), 0, stream>>>((const __half2*)Wh, xA, invD, xB, xA);              // x2, zero xA
    kMVh<<<mvGrid, dim3(256), 0, stream>>>((const __half2*)Wh, xB, invD, xA, xB);              // x3, zero xB
    kMVh<<<mvGrid, dim3(256), 0, stream>>>((const __half2*)Wh, xA, invD, xB, (float*)nullptr); // x4 (keep xA)
    // 8: per-batch finish + last-block global reduce
    kFinA<<<dim3(BB), dim3(256), 0, stream>>>(xA, xB, logD, part, bres, fincnt, out);
}